// Round 11
// baseline (244.873 us; speedup 1.0000x reference)
//
#include <hip/hip_runtime.h>

#define IMG   256
#define IMG2  65536
#define NB    64
#define NB2   128

// ---------------------------------------------------------------------------
// R11: cold-vs-warm test. Ledger: every COLD kernel (any structure) runs at
// 2.2-3.2 TB/s; warm label (R7 2nd launch) 5.8; read-free fill 6.8. The
// inter-iteration 470 MB reset fill evicts all inputs (L2+L3=288 MB), so all
// our kernels start cold. warm_kernel prefetches img+seg (117 MB) into L3 as
// a pure-read stream (14 independent float4 loads/thread, latency-tolerant),
// then the PROVEN R4 kernels run warm: warm -> label (seg) -> crops (img).
// ---------------------------------------------------------------------------

__global__ __launch_bounds__(256) void warm_kernel(
    const float* __restrict__ img,
    const float* __restrict__ seg8,
    const float* __restrict__ seg16,
    const float* __restrict__ seg32,
    float* __restrict__ wsf) {
    const int t = blockIdx.x * 256 + threadIdx.x;   // 0..524287
    const float4* __restrict__ pi = (const float4*)img;
    const float4* __restrict__ p8 = (const float4*)seg8;
    const float4* __restrict__ p6 = (const float4*)seg16;
    const float4* __restrict__ p2 = (const float4*)seg32;
    float4 a0 = pi[t];
    float4 a1 = pi[t + 524288];                     // img: 1048576 float4
    float4 b0 = p8[t];
    float4 b1 = p8[t + 524288];
    float4 b2 = p8[t + 1048576];
    float4 b3 = p8[t + 1572864];                    // seg8: 2097152 float4
    float4 c0 = p6[t];
    float4 c1 = p6[t + 524288];
    float4 c2 = p6[t + 1048576];
    float4 c3 = p6[t + 1572864];
    float4 d0 = p2[t];
    float4 d1 = p2[t + 524288];
    float4 d2 = p2[t + 1048576];
    float4 d3 = p2[t + 1572864];
    // cheap combine to keep loads live; one 4B store per thread (2 MB total)
    wsf[t] = (a0.x + a1.y) + (b0.x + b1.y + b2.z + b3.w)
           + (c0.x + c1.y + c2.z + c3.w) + (d0.x + d1.y + d2.z + d3.w);
}

__device__ __forceinline__ float4 norm4(float4 a, float mn, float inv) {
    float4 o;
    o.x = (a.x - mn) * inv; o.y = (a.y - mn) * inv;
    o.z = (a.z - mn) * inv; o.w = (a.w - mn) * inv;
    return o;
}

__device__ __forceinline__ void mm4(float4 a, float& mn, float& mx) {
    mn = fminf(mn, fminf(fminf(a.x, a.y), fminf(a.z, a.w)));
    mx = fmaxf(mx, fmaxf(fmaxf(a.x, a.y), fmaxf(a.z, a.w)));
}

// S=8: wave handles a 4-cell strip (8 rows x 32 cols) of one cell-row.
__device__ __forceinline__ void crops_s8(
    const float* __restrict__ img, const float* __restrict__ heat,
    float* __restrict__ out, int wid) {
    const int l   = threadIdx.x & 63;
    const int src = wid >> 8;
    const int rem = wid & 255;
    const int ci  = rem >> 3;
    const int st  = rem & 7;

    const int r    = l >> 3;
    const int cj   = st * 4 + ((l >> 1) & 3);
    const int o    = (l & 1) * 4;
    const int rowA = ci * 8 + r;
    const int rowB = ((ci == 0) ? 0 : ci * 8 - 4) + r;
    const int colA = st * 32 + (l & 7) * 4;
    const int colB = ((cj == 0) ? 0 : cj * 8 - 4) + o;

    const float* __restrict__ sp = img + (size_t)src * IMG2;
    const float4 a  = *(const float4*)(sp + rowA * IMG + colA);
    const float4 bq = *(const float4*)(sp + rowB * IMG + colB);

    float mnA = 3.4e38f, mxA = -3.4e38f, mnB = 3.4e38f, mxB = -3.4e38f;
    mm4(a, mnA, mxA); mm4(bq, mnB, mxB);
#pragma unroll
    for (int k = 0; k < 4; ++k) {
        const int off = (k == 0) ? 1 : (4 << k);  // 1, 8, 16, 32
        mnA = fminf(mnA, __shfl_xor(mnA, off, 64));
        mxA = fmaxf(mxA, __shfl_xor(mxA, off, 64));
        mnB = fminf(mnB, __shfl_xor(mnB, off, 64));
        mxB = fmaxf(mxB, __shfl_xor(mxB, off, 64));
    }
    const float hA = heat[(size_t)src * 1024 + ci * 32 + cj];
    const float hB = heat[(size_t)(src + NB) * 1024 + ci * 32 + cj];
    const float invA = (hA > 0.5f ? 1.0f : 0.0f) / (mxA - mnA + 1e-5f);
    const float invB = (hB > 0.5f ? 1.0f : 0.0f) / (mxB - mnB + 1e-5f);

    const size_t p = (size_t)src * IMG2 + rowA * IMG + colA;
    *(float4*)(out + p)                      = norm4(a,  mnA, invA);
    *(float4*)(out + p + (size_t)NB * IMG2)  = norm4(bq, mnB, invB);
}

// S=16: wave = one 16x16 cell; lane = r*4 + quarter.
__device__ __forceinline__ void crops_s16(
    const float* __restrict__ img, const float* __restrict__ heat,
    float* __restrict__ out, int wid) {
    const int l   = threadIdx.x & 63;
    const int src = wid >> 8;
    const int rem = wid & 255;
    const int ci  = rem >> 4;
    const int cj  = rem & 15;

    const int r    = l >> 2;
    const int o    = (l & 3) * 4;
    const int rowA = ci * 16 + r;
    const int rowB = ((ci == 0) ? 0 : ci * 16 - 4) + r;
    const int colA = cj * 16 + o;
    const int colB = ((cj == 0) ? 0 : cj * 16 - 4) + o;

    const float* __restrict__ sp = img + (size_t)src * IMG2;
    const float4 a  = *(const float4*)(sp + rowA * IMG + colA);
    const float4 bq = *(const float4*)(sp + rowB * IMG + colB);

    float mnA = 3.4e38f, mxA = -3.4e38f, mnB = 3.4e38f, mxB = -3.4e38f;
    mm4(a, mnA, mxA); mm4(bq, mnB, mxB);
#pragma unroll
    for (int off = 1; off < 64; off <<= 1) {
        mnA = fminf(mnA, __shfl_xor(mnA, off, 64));
        mxA = fmaxf(mxA, __shfl_xor(mxA, off, 64));
        mnB = fminf(mnB, __shfl_xor(mnB, off, 64));
        mxB = fmaxf(mxB, __shfl_xor(mxB, off, 64));
    }
    const float hA = heat[(size_t)src * 256 + ci * 16 + cj];
    const float hB = heat[(size_t)(src + NB) * 256 + ci * 16 + cj];
    const float invA = (hA > 0.5f ? 1.0f : 0.0f) / (mxA - mnA + 1e-5f);
    const float invB = (hB > 0.5f ? 1.0f : 0.0f) / (mxB - mnB + 1e-5f);

    const size_t p = (size_t)src * IMG2 + rowA * IMG + colA;
    *(float4*)(out + p)                      = norm4(a,  mnA, invA);
    *(float4*)(out + p + (size_t)NB * IMG2)  = norm4(bq, mnB, invB);
}

// S=32: wave = one 32x32 cell, 4 row-iterations held in registers.
__device__ __forceinline__ void crops_s32(
    const float* __restrict__ img, const float* __restrict__ heat,
    float* __restrict__ out, int wid) {
    const int l   = threadIdx.x & 63;
    const int src = wid >> 6;
    const int rem = wid & 63;
    const int ci  = rem >> 3;
    const int cj  = rem & 7;

    const int r0   = l >> 3;
    const int o    = (l & 7) * 4;
    const int rA   = ci * 32;
    const int rB   = (ci == 0) ? 0 : rA - 4;
    const int colA = cj * 32 + o;
    const int colB = ((cj == 0) ? 0 : cj * 32 - 4) + o;

    const float* __restrict__ sp = img + (size_t)src * IMG2;
    float4 a[4], bq[4];
#pragma unroll
    for (int k = 0; k < 4; ++k) {
        const int r = r0 + 8 * k;
        a[k]  = *(const float4*)(sp + (rA + r) * IMG + colA);
        bq[k] = *(const float4*)(sp + (rB + r) * IMG + colB);
    }
    float mnA = 3.4e38f, mxA = -3.4e38f, mnB = 3.4e38f, mxB = -3.4e38f;
#pragma unroll
    for (int k = 0; k < 4; ++k) { mm4(a[k], mnA, mxA); mm4(bq[k], mnB, mxB); }
#pragma unroll
    for (int off = 1; off < 64; off <<= 1) {
        mnA = fminf(mnA, __shfl_xor(mnA, off, 64));
        mxA = fmaxf(mxA, __shfl_xor(mxA, off, 64));
        mnB = fminf(mnB, __shfl_xor(mnB, off, 64));
        mxB = fmaxf(mxB, __shfl_xor(mxB, off, 64));
    }
    const float hA = heat[(size_t)src * 64 + ci * 8 + cj];
    const float hB = heat[(size_t)(src + NB) * 64 + ci * 8 + cj];
    const float invA = (hA > 0.5f ? 1.0f : 0.0f) / (mxA - mnA + 1e-5f);
    const float invB = (hB > 0.5f ? 1.0f : 0.0f) / (mxB - mnB + 1e-5f);

    float* __restrict__ dA = out + (size_t)src * IMG2;
    float* __restrict__ dB = out + (size_t)(src + NB) * IMG2;
#pragma unroll
    for (int k = 0; k < 4; ++k) {
        const int r = r0 + 8 * k;
        *(float4*)(dA + (rA + r) * IMG + colA) = norm4(a[k],  mnA, invA);
        *(float4*)(dB + (rA + r) * IMG + colA) = norm4(bq[k], mnB, invB);
    }
}

// ---------------------------------------------------------------------------
// label: one wave per row, 4 px per lane, float4 loads/stores. (R4, proven)
// ---------------------------------------------------------------------------
__device__ __forceinline__ void label_rows(
    const float* __restrict__ heat8,
    const float* __restrict__ heat16,
    const float* __restrict__ heat32,
    const float* __restrict__ seg8,
    const float* __restrict__ seg16,
    const float* __restrict__ seg32,
    float* __restrict__ out,
    int b, int u0) {
    const int wave = threadIdx.x >> 6;
    const int lane = threadIdx.x & 63;
    const int u    = u0 + wave;
    const int v0   = lane << 2;
    const int vs   = min(v0 + 4, 252);

    float nu[4] = {0.f, 0.f, 0.f, 0.f};
    float de[4] = {0.f, 0.f, 0.f, 0.f};

    if (u0 >= 32 && u0 <= 248) {
        const int i1 = u + 4;
#define SCALE_F(heat, seg, g, l, s)                                           \
        {                                                                     \
            const float* __restrict__ h1 = heat + b * (g * g);                \
            const float* __restrict__ h2 = heat + (NB + b) * (g * g);         \
            const float* __restrict__ r1 = seg + (size_t)b * IMG2 + u * IMG;  \
            const float* __restrict__ r2 =                                    \
                seg + (size_t)(NB + b) * IMG2 + i1 * IMG;                     \
            const float4 sd  = *(const float4*)(r1 + v0);                     \
            const float4 sg0 = *(const float4*)(r2 + v0);                     \
            const float4 sg1 = *(const float4*)(r2 + vs);                     \
            const float hd  = h1[(u >> l) * g + (v0 >> l)];                   \
            const float hg0 = h2[(i1 >> l) * g + (v0 >> l)];                  \
            const float hg1 = h2[(i1 >> l) * g + (vs >> l)];                  \
            const float md = (hd > 0.5f) ? 1.0f : 0.0f;                       \
            const float g0 = (hg0 > 0.5f) ? 1.0f : 0.0f;                      \
            const float g1 = (hg1 > 0.5f) ? 1.0f : 0.0f;                      \
            _Pragma("unroll")                                                 \
            for (int c = 0; c < 4; ++c) {                                     \
                const int v = v0 + c;                                         \
                const float m0 = (v < (s)) ? g0 : 0.0f;                       \
                const float m1 = (v >= (s) - 4 && v <= 251) ? g1 : 0.0f;      \
                float x = ((const float*)&sd)[c] * md;                        \
                x = fmaf(m0, ((const float*)&sg0)[c], x);                     \
                x = fmaf(m1, ((const float*)&sg1)[c], x);                     \
                nu[c] += x;                                                   \
                de[c] += md + m0 + m1;                                        \
            }                                                                 \
        }
        SCALE_F(heat32, seg32, 32, 3, 8)
        SCALE_F(heat16, seg16, 16, 4, 16)
        SCALE_F(heat8,  seg8,  8,  5, 32)
#undef SCALE_F
    } else {
        const int i0  = u;
        const int i1c = min(u + 4, 255);
#define SCALE_G(heat, seg, g, l, s)                                           \
        {                                                                     \
            const float* __restrict__ h1 = heat + b * (g * g);                \
            const float* __restrict__ h2 = heat + (NB + b) * (g * g);         \
            const float* __restrict__ r1 = seg + (size_t)b * IMG2 + u * IMG;  \
            const float* __restrict__ ra =                                    \
                seg + (size_t)(NB + b) * IMG2 + i0 * IMG;                     \
            const float* __restrict__ rb =                                    \
                seg + (size_t)(NB + b) * IMG2 + i1c * IMG;                    \
            const float4 sd  = *(const float4*)(r1 + v0);                     \
            const float4 a0q = *(const float4*)(ra + v0);                     \
            const float4 a1q = *(const float4*)(ra + vs);                     \
            const float4 b0q = *(const float4*)(rb + v0);                     \
            const float4 b1q = *(const float4*)(rb + vs);                     \
            const float hd  = h1[(u >> l) * g + (v0 >> l)];                   \
            const float hA0 = h2[(i0 >> l) * g + (v0 >> l)];                  \
            const float hA1 = h2[(i0 >> l) * g + (vs >> l)];                  \
            const float hB0 = h2[(i1c >> l) * g + (v0 >> l)];                 \
            const float hB1 = h2[(i1c >> l) * g + (vs >> l)];                 \
            const float miA = (u < (s)) ? 1.0f : 0.0f;                        \
            const float miB = (u >= (s) - 4 && u <= 251) ? 1.0f : 0.0f;       \
            const float md  = (hd > 0.5f) ? 1.0f : 0.0f;                      \
            const float gA0 = miA * ((hA0 > 0.5f) ? 1.0f : 0.0f);             \
            const float gA1 = miA * ((hA1 > 0.5f) ? 1.0f : 0.0f);             \
            const float gB0 = miB * ((hB0 > 0.5f) ? 1.0f : 0.0f);             \
            const float gB1 = miB * ((hB1 > 0.5f) ? 1.0f : 0.0f);             \
            _Pragma("unroll")                                                 \
            for (int c = 0; c < 4; ++c) {                                     \
                const int v = v0 + c;                                         \
                const float mj0 = (v < (s)) ? 1.0f : 0.0f;                    \
                const float mj1 = (v >= (s) - 4 && v <= 251) ? 1.0f : 0.0f;   \
                const float w00 = gA0 * mj0, w01 = gA1 * mj1;                 \
                const float w10 = gB0 * mj0, w11 = gB1 * mj1;                 \
                float x = ((const float*)&sd)[c] * md;                        \
                x = fmaf(w00, ((const float*)&a0q)[c], x);                    \
                x = fmaf(w01, ((const float*)&a1q)[c], x);                    \
                x = fmaf(w10, ((const float*)&b0q)[c], x);                    \
                x = fmaf(w11, ((const float*)&b1q)[c], x);                    \
                nu[c] += x;                                                   \
                de[c] += md + w00 + w01 + w10 + w11;                          \
            }                                                                 \
        }
        SCALE_G(heat32, seg32, 32, 3, 8)
        SCALE_G(heat16, seg16, 16, 4, 16)
        SCALE_G(heat8,  seg8,  8,  5, 32)
#undef SCALE_G
    }

    float4 o;
    o.x = nu[0] / (de[0] + 1e-10f);
    o.y = nu[1] / (de[1] + 1e-10f);
    o.z = nu[2] / (de[2] + 1e-10f);
    o.w = nu[3] / (de[3] + 1e-10f);
    *(float4*)(out + (size_t)b * IMG2 + u * IMG + v0) = o;
}

__global__ __launch_bounds__(256) void crops_kernel(
    const float* __restrict__ img,
    const float* __restrict__ heat8,
    const float* __restrict__ heat16,
    const float* __restrict__ heat32,
    float* __restrict__ out) {
    float* crops32 = out;                           // (128,1,256,256) s=8
    float* crops16 = out + (size_t)NB2 * IMG2;      // s=16
    float* crops8  = out + (size_t)2 * NB2 * IMG2;  // s=32

    const int cb  = blockIdx.x;                     // 0 .. 9215
    const int wid = cb * 4 + (threadIdx.x >> 6);
    if (cb < 4096) {
        crops_s8(img, heat32, crops32, wid);
    } else if (cb < 8192) {
        crops_s16(img, heat16, crops16, wid - 16384);
    } else {
        crops_s32(img, heat8, crops8, wid - 32768);
    }
}

__global__ __launch_bounds__(256) void label_kernel(
    const float* __restrict__ heat8,
    const float* __restrict__ heat16,
    const float* __restrict__ heat32,
    const float* __restrict__ seg8,
    const float* __restrict__ seg16,
    const float* __restrict__ seg32,
    float* __restrict__ out) {
    float* label = out + (size_t)3 * NB2 * IMG2;    // (64,1,256,256)
    const int t  = blockIdx.x;                      // 0 .. 4095
    label_rows(heat8, heat16, heat32, seg8, seg16, seg32, label,
               t >> 6, (t & 63) << 2);
}

extern "C" void kernel_launch(void* const* d_in, const int* in_sizes, int n_in,
                              void* d_out, int out_size, void* d_ws, size_t ws_size,
                              hipStream_t stream) {
    const float* img    = (const float*)d_in[0];
    const float* heat8  = (const float*)d_in[1];
    const float* heat16 = (const float*)d_in[2];
    const float* heat32 = (const float*)d_in[3];
    const float* seg8   = (const float*)d_in[4];
    const float* seg16  = (const float*)d_in[5];
    const float* seg32  = (const float*)d_in[6];

    // 1) pure-read prefetch of all inputs into L3 (latency-tolerant stream)
    warm_kernel<<<dim3(2048), 256, 0, stream>>>(
        img, seg8, seg16, seg32, (float*)d_ws);
    // 2) label consumes seg while L3-resident
    label_kernel<<<dim3(4096), 256, 0, stream>>>(
        heat8, heat16, heat32, seg8, seg16, seg32, (float*)d_out);
    // 3) crops consumes img (16.8 MB, survives label's 16.8 MB of writes)
    crops_kernel<<<dim3(9216), 256, 0, stream>>>(
        img, heat8, heat16, heat32, (float*)d_out);
}

// Round 12
// 240.737 us; speedup vs baseline: 1.0172x; 1.0172x over previous
//
#include <hip/hip_runtime.h>

#define IMG   256
#define IMG2  65536
#define NB    64
#define NB2   128

// ---------------------------------------------------------------------------
// R12 DIAGNOSTIC (output-safe): prestore_kernel zero-fills ALL of d_out in
// exact fill shape (grid-stride, 14 independent float4 stores/thread, no
// reads); label+crops then overwrite every byte -> absmax stays 0.
// Increment vs 223.66 decomposes as (our pure-store time) - (warm-output
// gain to crops/label):
//   +16 us  -> our stores run ~6.8 TB/s; warm outputs don't help.
//   +40-45  -> HIP-kernel stores to d_out are ~2.3 TB/s (write-path floor).
//   <=+5    -> stores fast AND warm-output big win -> keep prestore.
// R11 established: input warmth is irrelevant (cold-read theory dead);
// reads from compute kernels are fast (5.6-5.8 TB/s validated twice).
// ---------------------------------------------------------------------------

// d_out = (3*128 + 64) * 65536 floats = 7340032 float4 = 117.4 MB.
// 2048 blocks x 256 threads x 14 stores, stride 524288 float4 (8 MB sweeps).
__global__ __launch_bounds__(256) void prestore_kernel(float* __restrict__ out) {
    const int t = blockIdx.x * 256 + threadIdx.x;   // 0..524287
    float4* __restrict__ p = (float4*)out;
    const float4 z = make_float4(0.f, 0.f, 0.f, 0.f);
#pragma unroll
    for (int k = 0; k < 14; ++k) {
        p[t + k * 524288] = z;
    }
}

__device__ __forceinline__ float4 norm4(float4 a, float mn, float inv) {
    float4 o;
    o.x = (a.x - mn) * inv; o.y = (a.y - mn) * inv;
    o.z = (a.z - mn) * inv; o.w = (a.w - mn) * inv;
    return o;
}

__device__ __forceinline__ void mm4(float4 a, float& mn, float& mx) {
    mn = fminf(mn, fminf(fminf(a.x, a.y), fminf(a.z, a.w)));
    mx = fmaxf(mx, fmaxf(fmaxf(a.x, a.y), fmaxf(a.z, a.w)));
}

// S=8: wave handles a 4-cell strip (8 rows x 32 cols) of one cell-row.
__device__ __forceinline__ void crops_s8(
    const float* __restrict__ img, const float* __restrict__ heat,
    float* __restrict__ out, int wid) {
    const int l   = threadIdx.x & 63;
    const int src = wid >> 8;
    const int rem = wid & 255;
    const int ci  = rem >> 3;
    const int st  = rem & 7;

    const int r    = l >> 3;
    const int cj   = st * 4 + ((l >> 1) & 3);
    const int o    = (l & 1) * 4;
    const int rowA = ci * 8 + r;
    const int rowB = ((ci == 0) ? 0 : ci * 8 - 4) + r;
    const int colA = st * 32 + (l & 7) * 4;
    const int colB = ((cj == 0) ? 0 : cj * 8 - 4) + o;

    const float* __restrict__ sp = img + (size_t)src * IMG2;
    const float4 a  = *(const float4*)(sp + rowA * IMG + colA);
    const float4 bq = *(const float4*)(sp + rowB * IMG + colB);

    float mnA = 3.4e38f, mxA = -3.4e38f, mnB = 3.4e38f, mxB = -3.4e38f;
    mm4(a, mnA, mxA); mm4(bq, mnB, mxB);
#pragma unroll
    for (int k = 0; k < 4; ++k) {
        const int off = (k == 0) ? 1 : (4 << k);  // 1, 8, 16, 32
        mnA = fminf(mnA, __shfl_xor(mnA, off, 64));
        mxA = fmaxf(mxA, __shfl_xor(mxA, off, 64));
        mnB = fminf(mnB, __shfl_xor(mnB, off, 64));
        mxB = fmaxf(mxB, __shfl_xor(mxB, off, 64));
    }
    const float hA = heat[(size_t)src * 1024 + ci * 32 + cj];
    const float hB = heat[(size_t)(src + NB) * 1024 + ci * 32 + cj];
    const float invA = (hA > 0.5f ? 1.0f : 0.0f) / (mxA - mnA + 1e-5f);
    const float invB = (hB > 0.5f ? 1.0f : 0.0f) / (mxB - mnB + 1e-5f);

    const size_t p = (size_t)src * IMG2 + rowA * IMG + colA;
    *(float4*)(out + p)                      = norm4(a,  mnA, invA);
    *(float4*)(out + p + (size_t)NB * IMG2)  = norm4(bq, mnB, invB);
}

// S=16: wave = one 16x16 cell; lane = r*4 + quarter.
__device__ __forceinline__ void crops_s16(
    const float* __restrict__ img, const float* __restrict__ heat,
    float* __restrict__ out, int wid) {
    const int l   = threadIdx.x & 63;
    const int src = wid >> 8;
    const int rem = wid & 255;
    const int ci  = rem >> 4;
    const int cj  = rem & 15;

    const int r    = l >> 2;
    const int o    = (l & 3) * 4;
    const int rowA = ci * 16 + r;
    const int rowB = ((ci == 0) ? 0 : ci * 16 - 4) + r;
    const int colA = cj * 16 + o;
    const int colB = ((cj == 0) ? 0 : cj * 16 - 4) + o;

    const float* __restrict__ sp = img + (size_t)src * IMG2;
    const float4 a  = *(const float4*)(sp + rowA * IMG + colA);
    const float4 bq = *(const float4*)(sp + rowB * IMG + colB);

    float mnA = 3.4e38f, mxA = -3.4e38f, mnB = 3.4e38f, mxB = -3.4e38f;
    mm4(a, mnA, mxA); mm4(bq, mnB, mxB);
#pragma unroll
    for (int off = 1; off < 64; off <<= 1) {
        mnA = fminf(mnA, __shfl_xor(mnA, off, 64));
        mxA = fmaxf(mxA, __shfl_xor(mxA, off, 64));
        mnB = fminf(mnB, __shfl_xor(mnB, off, 64));
        mxB = fmaxf(mxB, __shfl_xor(mxB, off, 64));
    }
    const float hA = heat[(size_t)src * 256 + ci * 16 + cj];
    const float hB = heat[(size_t)(src + NB) * 256 + ci * 16 + cj];
    const float invA = (hA > 0.5f ? 1.0f : 0.0f) / (mxA - mnA + 1e-5f);
    const float invB = (hB > 0.5f ? 1.0f : 0.0f) / (mxB - mnB + 1e-5f);

    const size_t p = (size_t)src * IMG2 + rowA * IMG + colA;
    *(float4*)(out + p)                      = norm4(a,  mnA, invA);
    *(float4*)(out + p + (size_t)NB * IMG2)  = norm4(bq, mnB, invB);
}

// S=32: wave = one 32x32 cell, 4 row-iterations held in registers.
__device__ __forceinline__ void crops_s32(
    const float* __restrict__ img, const float* __restrict__ heat,
    float* __restrict__ out, int wid) {
    const int l   = threadIdx.x & 63;
    const int src = wid >> 6;
    const int rem = wid & 63;
    const int ci  = rem >> 3;
    const int cj  = rem & 7;

    const int r0   = l >> 3;
    const int o    = (l & 7) * 4;
    const int rA   = ci * 32;
    const int rB   = (ci == 0) ? 0 : rA - 4;
    const int colA = cj * 32 + o;
    const int colB = ((cj == 0) ? 0 : cj * 32 - 4) + o;

    const float* __restrict__ sp = img + (size_t)src * IMG2;
    float4 a[4], bq[4];
#pragma unroll
    for (int k = 0; k < 4; ++k) {
        const int r = r0 + 8 * k;
        a[k]  = *(const float4*)(sp + (rA + r) * IMG + colA);
        bq[k] = *(const float4*)(sp + (rB + r) * IMG + colB);
    }
    float mnA = 3.4e38f, mxA = -3.4e38f, mnB = 3.4e38f, mxB = -3.4e38f;
#pragma unroll
    for (int k = 0; k < 4; ++k) { mm4(a[k], mnA, mxA); mm4(bq[k], mnB, mxB); }
#pragma unroll
    for (int off = 1; off < 64; off <<= 1) {
        mnA = fminf(mnA, __shfl_xor(mnA, off, 64));
        mxA = fmaxf(mxA, __shfl_xor(mxA, off, 64));
        mnB = fminf(mnB, __shfl_xor(mnB, off, 64));
        mxB = fmaxf(mxB, __shfl_xor(mxB, off, 64));
    }
    const float hA = heat[(size_t)src * 64 + ci * 8 + cj];
    const float hB = heat[(size_t)(src + NB) * 64 + ci * 8 + cj];
    const float invA = (hA > 0.5f ? 1.0f : 0.0f) / (mxA - mnA + 1e-5f);
    const float invB = (hB > 0.5f ? 1.0f : 0.0f) / (mxB - mnB + 1e-5f);

    float* __restrict__ dA = out + (size_t)src * IMG2;
    float* __restrict__ dB = out + (size_t)(src + NB) * IMG2;
#pragma unroll
    for (int k = 0; k < 4; ++k) {
        const int r = r0 + 8 * k;
        *(float4*)(dA + (rA + r) * IMG + colA) = norm4(a[k],  mnA, invA);
        *(float4*)(dB + (rA + r) * IMG + colA) = norm4(bq[k], mnB, invB);
    }
}

// ---------------------------------------------------------------------------
// label: one wave per row, 4 px per lane, float4 loads/stores. (R4, proven)
// ---------------------------------------------------------------------------
__device__ __forceinline__ void label_rows(
    const float* __restrict__ heat8,
    const float* __restrict__ heat16,
    const float* __restrict__ heat32,
    const float* __restrict__ seg8,
    const float* __restrict__ seg16,
    const float* __restrict__ seg32,
    float* __restrict__ out,
    int b, int u0) {
    const int wave = threadIdx.x >> 6;
    const int lane = threadIdx.x & 63;
    const int u    = u0 + wave;
    const int v0   = lane << 2;
    const int vs   = min(v0 + 4, 252);

    float nu[4] = {0.f, 0.f, 0.f, 0.f};
    float de[4] = {0.f, 0.f, 0.f, 0.f};

    if (u0 >= 32 && u0 <= 248) {
        const int i1 = u + 4;
#define SCALE_F(heat, seg, g, l, s)                                           \
        {                                                                     \
            const float* __restrict__ h1 = heat + b * (g * g);                \
            const float* __restrict__ h2 = heat + (NB + b) * (g * g);         \
            const float* __restrict__ r1 = seg + (size_t)b * IMG2 + u * IMG;  \
            const float* __restrict__ r2 =                                    \
                seg + (size_t)(NB + b) * IMG2 + i1 * IMG;                     \
            const float4 sd  = *(const float4*)(r1 + v0);                     \
            const float4 sg0 = *(const float4*)(r2 + v0);                     \
            const float4 sg1 = *(const float4*)(r2 + vs);                     \
            const float hd  = h1[(u >> l) * g + (v0 >> l)];                   \
            const float hg0 = h2[(i1 >> l) * g + (v0 >> l)];                  \
            const float hg1 = h2[(i1 >> l) * g + (vs >> l)];                  \
            const float md = (hd > 0.5f) ? 1.0f : 0.0f;                       \
            const float g0 = (hg0 > 0.5f) ? 1.0f : 0.0f;                      \
            const float g1 = (hg1 > 0.5f) ? 1.0f : 0.0f;                      \
            _Pragma("unroll")                                                 \
            for (int c = 0; c < 4; ++c) {                                     \
                const int v = v0 + c;                                         \
                const float m0 = (v < (s)) ? g0 : 0.0f;                       \
                const float m1 = (v >= (s) - 4 && v <= 251) ? g1 : 0.0f;      \
                float x = ((const float*)&sd)[c] * md;                        \
                x = fmaf(m0, ((const float*)&sg0)[c], x);                     \
                x = fmaf(m1, ((const float*)&sg1)[c], x);                     \
                nu[c] += x;                                                   \
                de[c] += md + m0 + m1;                                        \
            }                                                                 \
        }
        SCALE_F(heat32, seg32, 32, 3, 8)
        SCALE_F(heat16, seg16, 16, 4, 16)
        SCALE_F(heat8,  seg8,  8,  5, 32)
#undef SCALE_F
    } else {
        const int i0  = u;
        const int i1c = min(u + 4, 255);
#define SCALE_G(heat, seg, g, l, s)                                           \
        {                                                                     \
            const float* __restrict__ h1 = heat + b * (g * g);                \
            const float* __restrict__ h2 = heat + (NB + b) * (g * g);         \
            const float* __restrict__ r1 = seg + (size_t)b * IMG2 + u * IMG;  \
            const float* __restrict__ ra =                                    \
                seg + (size_t)(NB + b) * IMG2 + i0 * IMG;                     \
            const float* __restrict__ rb =                                    \
                seg + (size_t)(NB + b) * IMG2 + i1c * IMG;                    \
            const float4 sd  = *(const float4*)(r1 + v0);                     \
            const float4 a0q = *(const float4*)(ra + v0);                     \
            const float4 a1q = *(const float4*)(ra + vs);                     \
            const float4 b0q = *(const float4*)(rb + v0);                     \
            const float4 b1q = *(const float4*)(rb + vs);                     \
            const float hd  = h1[(u >> l) * g + (v0 >> l)];                   \
            const float hA0 = h2[(i0 >> l) * g + (v0 >> l)];                  \
            const float hA1 = h2[(i0 >> l) * g + (vs >> l)];                  \
            const float hB0 = h2[(i1c >> l) * g + (v0 >> l)];                 \
            const float hB1 = h2[(i1c >> l) * g + (vs >> l)];                 \
            const float miA = (u < (s)) ? 1.0f : 0.0f;                        \
            const float miB = (u >= (s) - 4 && u <= 251) ? 1.0f : 0.0f;       \
            const float md  = (hd > 0.5f) ? 1.0f : 0.0f;                      \
            const float gA0 = miA * ((hA0 > 0.5f) ? 1.0f : 0.0f);             \
            const float gA1 = miA * ((hA1 > 0.5f) ? 1.0f : 0.0f);             \
            const float gB0 = miB * ((hB0 > 0.5f) ? 1.0f : 0.0f);             \
            const float gB1 = miB * ((hB1 > 0.5f) ? 1.0f : 0.0f);             \
            _Pragma("unroll")                                                 \
            for (int c = 0; c < 4; ++c) {                                     \
                const int v = v0 + c;                                         \
                const float mj0 = (v < (s)) ? 1.0f : 0.0f;                    \
                const float mj1 = (v >= (s) - 4 && v <= 251) ? 1.0f : 0.0f;   \
                const float w00 = gA0 * mj0, w01 = gA1 * mj1;                 \
                const float w10 = gB0 * mj0, w11 = gB1 * mj1;                 \
                float x = ((const float*)&sd)[c] * md;                        \
                x = fmaf(w00, ((const float*)&a0q)[c], x);                    \
                x = fmaf(w01, ((const float*)&a1q)[c], x);                    \
                x = fmaf(w10, ((const float*)&b0q)[c], x);                    \
                x = fmaf(w11, ((const float*)&b1q)[c], x);                    \
                nu[c] += x;                                                   \
                de[c] += md + w00 + w01 + w10 + w11;                          \
            }                                                                 \
        }
        SCALE_G(heat32, seg32, 32, 3, 8)
        SCALE_G(heat16, seg16, 16, 4, 16)
        SCALE_G(heat8,  seg8,  8,  5, 32)
#undef SCALE_G
    }

    float4 o;
    o.x = nu[0] / (de[0] + 1e-10f);
    o.y = nu[1] / (de[1] + 1e-10f);
    o.z = nu[2] / (de[2] + 1e-10f);
    o.w = nu[3] / (de[3] + 1e-10f);
    *(float4*)(out + (size_t)b * IMG2 + u * IMG + v0) = o;
}

__global__ __launch_bounds__(256) void crops_kernel(
    const float* __restrict__ img,
    const float* __restrict__ heat8,
    const float* __restrict__ heat16,
    const float* __restrict__ heat32,
    float* __restrict__ out) {
    float* crops32 = out;                           // (128,1,256,256) s=8
    float* crops16 = out + (size_t)NB2 * IMG2;      // s=16
    float* crops8  = out + (size_t)2 * NB2 * IMG2;  // s=32

    const int cb  = blockIdx.x;                     // 0 .. 9215
    const int wid = cb * 4 + (threadIdx.x >> 6);
    if (cb < 4096) {
        crops_s8(img, heat32, crops32, wid);
    } else if (cb < 8192) {
        crops_s16(img, heat16, crops16, wid - 16384);
    } else {
        crops_s32(img, heat8, crops8, wid - 32768);
    }
}

__global__ __launch_bounds__(256) void label_kernel(
    const float* __restrict__ heat8,
    const float* __restrict__ heat16,
    const float* __restrict__ heat32,
    const float* __restrict__ seg8,
    const float* __restrict__ seg16,
    const float* __restrict__ seg32,
    float* __restrict__ out) {
    float* label = out + (size_t)3 * NB2 * IMG2;    // (64,1,256,256)
    const int t  = blockIdx.x;                      // 0 .. 4095
    label_rows(heat8, heat16, heat32, seg8, seg16, seg32, label,
               t >> 6, (t & 63) << 2);
}

extern "C" void kernel_launch(void* const* d_in, const int* in_sizes, int n_in,
                              void* d_out, int out_size, void* d_ws, size_t ws_size,
                              hipStream_t stream) {
    const float* img    = (const float*)d_in[0];
    const float* heat8  = (const float*)d_in[1];
    const float* heat16 = (const float*)d_in[2];
    const float* heat32 = (const float*)d_in[3];
    const float* seg8   = (const float*)d_in[4];
    const float* seg16  = (const float*)d_in[5];
    const float* seg32  = (const float*)d_in[6];

    // DIAGNOSTIC: zero-fill all of d_out (fill shape), then overwrite.
    prestore_kernel<<<dim3(2048), 256, 0, stream>>>((float*)d_out);
    label_kernel<<<dim3(4096), 256, 0, stream>>>(
        heat8, heat16, heat32, seg8, seg16, seg32, (float*)d_out);
    crops_kernel<<<dim3(9216), 256, 0, stream>>>(
        img, heat8, heat16, heat32, (float*)d_out);
}